// Round 15
// baseline (163.473 us; speedup 1.0000x reference)
//
#include <hip/hip_runtime.h>
#include <math.h>

#define D 2048
#define M 512

// Spectral interval: sv in [0.48,1.52] -> t=s^2 in [0.2304,2.3104]
#define MCEN 1.2704f
#define HRAD 1.04f

typedef unsigned short u16;
typedef unsigned int u32;
typedef __attribute__((ext_vector_type(8))) short bf16x8;
typedef __attribute__((ext_vector_type(4))) float f32x4;

__device__ inline u16 f2bf(float f) {
    union { float f; unsigned u; } v; v.f = f;
    unsigned r = v.u + 0x7fffu + ((v.u >> 16) & 1u);  // RNE
    return (u16)(r >> 16);
}
__device__ inline float bf2f(u16 h) {
    union { float f; unsigned u; } v; v.u = ((unsigned)h) << 16;
    return v.f;
}

// per-wave K-range fragment MACs into acc pair (split-bf16 3-MFMA scheme)
__device__ inline void mm_ks(const u16* __restrict__ aHi,
                             const u16* __restrict__ aLo, int lda,
                             const u16* __restrict__ bHi,
                             const u16* __restrict__ bLo, int ldb,
                             int K, int lm, int lq, f32x4& a1, f32x4& a2) {
    const u16* ah = aHi + (size_t)lm * lda + lq * 8;
    const u16* al = aLo + (size_t)lm * lda + lq * 8;
    const u16* bh = bHi + (size_t)lm * ldb + lq * 8;
    const u16* bl = bLo + (size_t)lm * ldb + lq * 8;
    #pragma unroll 8
    for (int k = 0; k < K; k += 32) {
        const bf16x8 fah = *(const bf16x8*)(ah + k);
        const bf16x8 fal = *(const bf16x8*)(al + k);
        const bf16x8 fbh = *(const bf16x8*)(bh + k);
        const bf16x8 fbl = *(const bf16x8*)(bl + k);
        a1 = __builtin_amdgcn_mfma_f32_16x16x32_bf16(fah, fbh, a1, 0, 0, 0);
        a2 = __builtin_amdgcn_mfma_f32_16x16x32_bf16(fah, fbl, a2, 0, 0, 0);
        a2 = __builtin_amdgcn_mfma_f32_16x16x32_bf16(fal, fbh, a2, 0, 0, 0);
    }
}

// 32x32 tile of U·V per 512-thread block: 8 waves = 4 quadrants x 2 K-halves.
__device__ inline void tile32(const u16* __restrict__ Uh, const u16* __restrict__ Ul, int lda,
                              const u16* __restrict__ Vh, const u16* __restrict__ Vl, int ldb,
                              int K, int i0, int j0, int t, float* red,
                              float val[2], int row[2], int col[2]) {
    const int w = t >> 6, lane = t & 63;
    const int lm = lane & 15, lq = lane >> 4;
    const int q = w >> 1, kh = w & 1;
    const int qi = q >> 1, qj = q & 1;
    const int Kh = K >> 1;
    const size_t ko = (size_t)kh * Kh;
    f32x4 a1 = {0.f, 0.f, 0.f, 0.f}, a2 = {0.f, 0.f, 0.f, 0.f};
    mm_ks(Uh + (size_t)(i0 + 16 * qi) * lda + ko, Ul + (size_t)(i0 + 16 * qi) * lda + ko, lda,
          Vh + (size_t)(j0 + 16 * qj) * ldb + ko, Vl + (size_t)(j0 + 16 * qj) * ldb + ko, ldb,
          Kh, lm, lq, a1, a2);
    const f32x4 s = a1 + a2;
    #pragma unroll
    for (int r = 0; r < 4; ++r) red[w * 256 + (lq * 4 + r) * 16 + lm] = s[r];
    __syncthreads();
    #pragma unroll
    for (int e = 0; e < 2; ++e) {
        const int ee = t + e * 512;
        const int qq = ee >> 8, p = ee & 255;
        val[e] = red[qq * 512 + p] + red[qq * 512 + 256 + p];
        row[e] = i0 + 16 * (qq >> 1) + (p >> 4);
        col[e] = j0 + 16 * (qq & 1) + (p & 15);
    }
}

// LDS swizzle for the fused gram staging
__device__ inline int swz(int c) { return (((c >> 2) ^ c) & 3) << 3; }

// ---- d1: fused transpose + gram -> Ghat = (X^T X - m I)/h, split bf16.
// R14-proven body (128-k chunks, 64 KB double-buffered LDS); epilogue emits
// Ghat instead of G/C1. j0==0 blocks also emit Xhi/Xlo row-major.
__global__ __launch_bounds__(512) void gram_fx(
    const float* __restrict__ X,
    u16* __restrict__ Gh, u16* __restrict__ Gl,
    u16* __restrict__ Xhi, u16* __restrict__ Xlo) {
    __shared__ __align__(16) char smem[65536];
    u32* LT = (u32*)smem;
    float* red = (float*)smem;

    const int i0 = (blockIdx.x >> 4) * 32, j0 = (blockIdx.x & 15) * 32;
    const int t = threadIdx.x;
    const int w = t >> 6, lane = t & 63;
    const int lm = lane & 15, lq = lane >> 4;
    const int q = w >> 1, kh = w & 1;
    const int qi = q >> 1, qj = q & 1;
    const bool emitX = (j0 == 0);

    const int r = t >> 3;
    const int c4 = (t & 7) * 4;

    const float* pa = X + (size_t)r * M + i0 + c4;
    const float* pb = X + (size_t)r * M + j0 + c4;
    float4 fA0 = *(const float4*)pa;
    float4 fA1 = *(const float4*)(pa + (size_t)64 * M);
    float4 fB0 = *(const float4*)pb;
    float4 fB1 = *(const float4*)(pb + (size_t)64 * M);

    f32x4 a1 = {0.f, 0.f, 0.f, 0.f}, a2 = {0.f, 0.f, 0.f, 0.f};
    int buf = 0;

    for (int k0 = 0; k0 < D; k0 += 128) {
        u32 pkA0[4], pkA1[4], pkB0[4], pkB1[4];
        {
            const float va0[4] = {fA0.x, fA0.y, fA0.z, fA0.w};
            const float va1[4] = {fA1.x, fA1.y, fA1.z, fA1.w};
            const float vb0[4] = {fB0.x, fB0.y, fB0.z, fB0.w};
            const float vb1[4] = {fB1.x, fB1.y, fB1.z, fB1.w};
            #pragma unroll
            for (int e = 0; e < 4; ++e) {
                union { float f; u32 u; } u0, u1, u2, u3, h0, h1, h2, h3;
                u0.f = va0[e]; u1.f = va1[e]; u2.f = vb0[e]; u3.f = vb1[e];
                h0.u = u0.u & 0xFFFF0000u;
                h1.u = u1.u & 0xFFFF0000u;
                h2.u = u2.u & 0xFFFF0000u;
                h3.u = u3.u & 0xFFFF0000u;
                pkA0[e] = h0.u | f2bf(va0[e] - h0.f);
                pkA1[e] = h1.u | f2bf(va1[e] - h1.f);
                pkB0[e] = h2.u | f2bf(vb0[e] - h2.f);
                pkB1[e] = h3.u | f2bf(vb1[e] - h3.f);
            }
        }
        u32* A0 = LT + buf * 4096;
        u32* B0 = LT + (2 + buf) * 4096;
        #pragma unroll
        for (int e = 0; e < 4; ++e) {
            const int c = c4 + e;
            const int rk = r ^ swz(c);
            A0[c * 128 + rk] = pkA0[e];
            A0[c * 128 + rk + 64] = pkA1[e];
            B0[c * 128 + rk] = pkB0[e];
            B0[c * 128 + rk + 64] = pkB1[e];
        }
        if (emitX) {
            uint2 hw, lw;
            hw.x = (pkA0[0] >> 16) | (pkA0[1] & 0xFFFF0000u);
            hw.y = (pkA0[2] >> 16) | (pkA0[3] & 0xFFFF0000u);
            lw.x = (pkA0[0] & 0xFFFFu) | (pkA0[1] << 16);
            lw.y = (pkA0[2] & 0xFFFFu) | (pkA0[3] << 16);
            *(uint2*)(Xhi + (size_t)(k0 + r) * M + i0 + c4) = hw;
            *(uint2*)(Xlo + (size_t)(k0 + r) * M + i0 + c4) = lw;
            hw.x = (pkA1[0] >> 16) | (pkA1[1] & 0xFFFF0000u);
            hw.y = (pkA1[2] >> 16) | (pkA1[3] & 0xFFFF0000u);
            lw.x = (pkA1[0] & 0xFFFFu) | (pkA1[1] << 16);
            lw.y = (pkA1[2] & 0xFFFFu) | (pkA1[3] << 16);
            *(uint2*)(Xhi + (size_t)(k0 + r + 64) * M + i0 + c4) = hw;
            *(uint2*)(Xlo + (size_t)(k0 + r + 64) * M + i0 + c4) = lw;
        }
        __syncthreads();
        if (k0 + 128 < D) {
            fA0 = *(const float4*)(pa + (size_t)(k0 + 128) * M);
            fA1 = *(const float4*)(pa + (size_t)(k0 + 192) * M);
            fB0 = *(const float4*)(pb + (size_t)(k0 + 128) * M);
            fB1 = *(const float4*)(pb + (size_t)(k0 + 192) * M);
        }
        #pragma unroll
        for (int ks = 0; ks < 64; ks += 32) {
            const int ca = 16 * qi + lm, cb = 16 * qj + lm;
            const int kb = kh * 64 + ks + lq * 8;
            const u32* ap = A0 + ca * 128 + (kb ^ swz(ca));
            const u32* bp = B0 + cb * 128 + (kb ^ swz(cb));
            u32 au[8], bu[8];
            *(uint4*)(au) = *(const uint4*)(ap);
            *(uint4*)(au + 4) = *(const uint4*)(ap + 4);
            *(uint4*)(bu) = *(const uint4*)(bp);
            *(uint4*)(bu + 4) = *(const uint4*)(bp + 4);
            u32 ahp[4], alp[4], bhp[4], blp[4];
            #pragma unroll
            for (int e = 0; e < 4; ++e) {
                ahp[e] = (au[2 * e] >> 16) | (au[2 * e + 1] & 0xFFFF0000u);
                alp[e] = (au[2 * e] & 0xFFFFu) | (au[2 * e + 1] << 16);
                bhp[e] = (bu[2 * e] >> 16) | (bu[2 * e + 1] & 0xFFFF0000u);
                blp[e] = (bu[2 * e] & 0xFFFFu) | (bu[2 * e + 1] << 16);
            }
            const bf16x8 fah = *(const bf16x8*)ahp;
            const bf16x8 fal = *(const bf16x8*)alp;
            const bf16x8 fbh = *(const bf16x8*)bhp;
            const bf16x8 fbl = *(const bf16x8*)blp;
            a1 = __builtin_amdgcn_mfma_f32_16x16x32_bf16(fah, fbh, a1, 0, 0, 0);
            a2 = __builtin_amdgcn_mfma_f32_16x16x32_bf16(fah, fbl, a2, 0, 0, 0);
            a2 = __builtin_amdgcn_mfma_f32_16x16x32_bf16(fal, fbh, a2, 0, 0, 0);
        }
        buf ^= 1;
    }

    __syncthreads();
    const f32x4 s = a1 + a2;
    #pragma unroll
    for (int e = 0; e < 4; ++e) red[w * 256 + (lq * 4 + e) * 16 + lm] = s[e];
    __syncthreads();
    #pragma unroll
    for (int e = 0; e < 2; ++e) {
        const int ee = t + e * 512;
        const int qq = ee >> 8, p = ee & 255;
        const float g = red[qq * 512 + p] + red[qq * 512 + 256 + p];
        const int row = i0 + 16 * (qq >> 1) + (p >> 4);
        const int col = j0 + 16 * (qq & 1) + (p & 15);
        const size_t idx = (size_t)row * M + col;
        const float gh_ = (g - (row == col ? MCEN : 0.0f)) * (1.0f / HRAD);
        const u16 h = f2bf(gh_);
        Gh[idx] = h; Gl[idx] = f2bf(gh_ - bf2f(h));
    }
}

// ---- d2: G2 = Ghat^2; epilogue also emits A1 = c3 I + c4 Ghat + c5 G2 and
//          A3 = c9 I + c10 Ghat + c11 G2.
__global__ __launch_bounds__(512) void sq_c(
    const u16* __restrict__ Gh, const u16* __restrict__ Gl,
    u16* __restrict__ G2h, u16* __restrict__ G2l,
    u16* __restrict__ A1h, u16* __restrict__ A1l,
    u16* __restrict__ A3h, u16* __restrict__ A3l,
    const float c3, const float c4, const float c5,
    const float c9, const float c10, const float c11) {
    __shared__ float red[2048];
    const int i0 = (blockIdx.x >> 4) * 32, j0 = (blockIdx.x & 15) * 32;
    float val[2]; int row[2], col[2];
    tile32(Gh, Gl, M, Gh, Gl, M, 512, i0, j0, threadIdx.x, red, val, row, col);
    #pragma unroll
    for (int e = 0; e < 2; ++e) {
        const size_t idx = (size_t)row[e] * M + col[e];
        const float g2 = val[e];
        const float g = bf2f(Gh[idx]) + bf2f(Gl[idx]);
        const float dg = (row[e] == col[e]) ? 1.0f : 0.0f;
        u16 h = f2bf(g2);
        G2h[idx] = h; G2l[idx] = f2bf(g2 - bf2f(h));
        const float a1v = c3 * dg + c4 * g + c5 * g2;
        h = f2bf(a1v);
        A1h[idx] = h; A1l[idx] = f2bf(a1v - bf2f(h));
        const float a3v = c9 * dg + c10 * g + c11 * g2;
        h = f2bf(a3v);
        A3h[idx] = h; A3l[idx] = f2bf(a3v - bf2f(h));
    }
}

// ---- d3: plain mm: O = U·V (Q = Ghat·G2).
__global__ __launch_bounds__(512) void mm32(
    const u16* __restrict__ Uh, const u16* __restrict__ Ul,
    const u16* __restrict__ Vh, const u16* __restrict__ Vl,
    u16* __restrict__ Oh, u16* __restrict__ Ol) {
    __shared__ float red[2048];
    const int i0 = (blockIdx.x >> 4) * 32, j0 = (blockIdx.x & 15) * 32;
    float val[2]; int row[2], col[2];
    tile32(Uh, Ul, M, Vh, Vl, M, 512, i0, j0, threadIdx.x, red, val, row, col);
    #pragma unroll
    for (int e = 0; e < 2; ++e) {
        const size_t idx = (size_t)row[e] * M + col[e];
        const u16 h = f2bf(val[e]);
        Oh[idx] = h; Ol[idx] = f2bf(val[e] - bf2f(h));
    }
}

// ---- d4: three jobs (768 blocks):
//  j0: V = Q·A1 + (c0 I + c1 Ghat + c2 G2)
//  j1: U = Q·A3 + (c6 I + c7 Ghat + c8 G2)
//  j2: Q2 = Q·Q
__global__ __launch_bounds__(512) void triple32(
    const u16* __restrict__ Qh, const u16* __restrict__ Ql,
    const u16* __restrict__ A1h, const u16* __restrict__ A1l,
    const u16* __restrict__ A3h, const u16* __restrict__ A3l,
    const u16* __restrict__ Gh, const u16* __restrict__ Gl,
    const u16* __restrict__ G2h, const u16* __restrict__ G2l,
    u16* __restrict__ Vh, u16* __restrict__ Vl,
    u16* __restrict__ Uh, u16* __restrict__ Ul,
    u16* __restrict__ Q2h, u16* __restrict__ Q2l,
    const float c0, const float c1, const float c2,
    const float c6, const float c7, const float c8) {
    __shared__ float red[2048];
    const int job = blockIdx.x >> 8, tile = blockIdx.x & 255;
    const int i0 = (tile >> 4) * 32, j0 = (tile & 15) * 32;
    const u16* Bh_ = (job == 0) ? A1h : (job == 1) ? A3h : Qh;
    const u16* Bl_ = (job == 0) ? A1l : (job == 1) ? A3l : Ql;
    float val[2]; int row[2], col[2];
    tile32(Qh, Ql, M, Bh_, Bl_, M, 512, i0, j0, threadIdx.x, red, val, row, col);
    #pragma unroll
    for (int e = 0; e < 2; ++e) {
        const size_t idx = (size_t)row[e] * M + col[e];
        if (job == 2) {
            const u16 h = f2bf(val[e]);
            Q2h[idx] = h; Q2l[idx] = f2bf(val[e] - bf2f(h));
        } else {
            const float dg = (row[e] == col[e]) ? 1.0f : 0.0f;
            const float g = bf2f(Gh[idx]) + bf2f(Gl[idx]);
            const float g2 = bf2f(G2h[idx]) + bf2f(G2l[idx]);
            float v;
            u16* Oh; u16* Ol;
            if (job == 0) { v = val[e] + c0 * dg + c1 * g + c2 * g2; Oh = Vh; Ol = Vl; }
            else          { v = val[e] + c6 * dg + c7 * g + c8 * g2; Oh = Uh; Ol = Ul; }
            const u16 h = f2bf(v);
            Oh[idx] = h; Ol[idx] = f2bf(v - bf2f(h));
        }
    }
}

// ---- d5: B = Q2·U + r12·(Q2·Q2) + V
__global__ __launch_bounds__(512) void bfin32(
    const u16* __restrict__ Q2h, const u16* __restrict__ Q2l,
    const u16* __restrict__ Uh, const u16* __restrict__ Ul,
    const u16* __restrict__ Vh, const u16* __restrict__ Vl,
    u16* __restrict__ Bh, u16* __restrict__ Bl,
    const float r12) {
    __shared__ float red[2048];
    const int i0 = (blockIdx.x >> 4) * 32, j0 = (blockIdx.x & 15) * 32;
    float val1[2], val2[2]; int row[2], col[2];
    tile32(Q2h, Q2l, M, Uh, Ul, M, 512, i0, j0, threadIdx.x, red, val1, row, col);
    __syncthreads();
    tile32(Q2h, Q2l, M, Q2h, Q2l, M, 512, i0, j0, threadIdx.x, red, val2, row, col);
    #pragma unroll
    for (int e = 0; e < 2; ++e) {
        const size_t idx = (size_t)row[e] * M + col[e];
        const float b = val1[e] + r12 * val2[e] + bf2f(Vh[idx]) + bf2f(Vl[idx]);
        const u16 h = f2bf(b);
        Bh[idx] = h; Bl[idx] = f2bf(b - bf2f(h));
    }
}

// ---- d6: out = X·B (fp32). 32x32 tile/block, 4 full-K quadrant waves.
__global__ __launch_bounds__(256) void final32(
    const u16* __restrict__ Xhi, const u16* __restrict__ Xlo,
    const u16* __restrict__ Bh, const u16* __restrict__ Bl,
    float* __restrict__ out) {
    const int t = threadIdx.x;
    const int i0 = (blockIdx.x >> 4) * 32, j0 = (blockIdx.x & 15) * 32;
    const int w = t >> 6, lane = t & 63;
    const int lm = lane & 15, lq = lane >> 4;
    const int qi = w >> 1, qj = w & 1;
    f32x4 a1 = {0.f, 0.f, 0.f, 0.f}, a2 = {0.f, 0.f, 0.f, 0.f};
    mm_ks(Xhi + (size_t)(i0 + 16 * qi) * M, Xlo + (size_t)(i0 + 16 * qi) * M, M,
          Bh + (size_t)(j0 + 16 * qj) * M, Bl + (size_t)(j0 + 16 * qj) * M, M,
          512, lm, lq, a1, a2);
    const f32x4 acc = a1 + a2;
    float* o = out + (size_t)(i0 + 16 * qi + lq * 4) * M + j0 + 16 * qj + lm;
    #pragma unroll
    for (int r = 0; r < 4; ++r) o[(size_t)r * M] = acc[r];
}

extern "C" void kernel_launch(void* const* d_in, const int* in_sizes, int n_in,
                              void* d_out, int out_size, void* d_ws, size_t ws_size,
                              hipStream_t stream) {
    const float* Xin = (const float*)d_in[0];
    float* out = (float*)d_out;
    u16* w = (u16*)d_ws;

    // ---- host: degree-12 Legendre-series coefficients of t^{-1/2} on
    // [m-h, m+h], in the u = (t-m)/h monomial basis (double precision).
    double Pm[13][13];
    for (int i = 0; i < 13; ++i)
        for (int k = 0; k < 13; ++k) Pm[i][k] = 0.0;
    Pm[0][0] = 1.0; Pm[1][1] = 1.0;
    for (int n = 1; n < 12; ++n)
        for (int k = 0; k <= n + 1; ++k) {
            const double t1 = (k >= 1) ? (2.0 * n + 1.0) * Pm[n][k - 1] : 0.0;
            const double t2 = (double)n * Pm[n - 1][k];
            Pm[n + 1][k] = (t1 - t2) / (double)(n + 1);
        }
    const double m_ = (double)MCEN, h_ = (double)HRAD;
    const double mh = m_ / h_;
    const double z = mh - sqrt(mh * mh - 1.0);
    const double scale = sqrt(2.0 * z / h_);
    float r[13];
    for (int k = 0; k < 13; ++k) {
        double s = 0.0, zn = 1.0;
        for (int n = 0; n < 13; ++n) {
            s += zn * Pm[n][k];
            zn *= -z;
        }
        r[k] = (float)(scale * s);
    }

    // ---- buffers
    u16* Xhi = w;                    // D*M = 1048576 each
    u16* Xlo = w + 1048576u;
    u16* q = w + 2097152u;           // M*M = 262144 each
    u16* Gh  = q;             u16* Gl  = q + 262144u;
    u16* G2h = q + 524288u;   u16* G2l = q + 786432u;
    u16* A1h = q + 1048576u;  u16* A1l = q + 1310720u;
    u16* A3h = q + 1572864u;  u16* A3l = q + 1835008u;
    u16* Qh  = q + 2097152u;  u16* Ql  = q + 2359296u;
    u16* Vh  = q + 2621440u;  u16* Vl  = q + 2883584u;
    u16* Uh  = q + 3145728u;  u16* Ul  = q + 3407872u;
    u16* Q2h = q + 3670016u;  u16* Q2l = q + 3932160u;
    u16* Bh  = q + 4194304u;  u16* Bl  = q + 4456448u;

    // d1: Ghat = (X^T X - m I)/h ; also Xhi/Xlo
    gram_fx<<<256, 512, 0, stream>>>(Xin, Gh, Gl, Xhi, Xlo);
    // d2: G2 = Ghat^2 ; A1, A3 combos
    sq_c<<<256, 512, 0, stream>>>(Gh, Gl, G2h, G2l, A1h, A1l, A3h, A3l,
                                  r[3], r[4], r[5], r[9], r[10], r[11]);
    // d3: Q = Ghat·G2  (= Ghat^3)
    mm32<<<256, 512, 0, stream>>>(Gh, Gl, G2h, G2l, Qh, Ql);
    // d4: V = Q·A1 + A0 || U = Q·A3 + A2 || Q2 = Q·Q
    triple32<<<768, 512, 0, stream>>>(Qh, Ql, A1h, A1l, A3h, A3l,
                                      Gh, Gl, G2h, G2l,
                                      Vh, Vl, Uh, Ul, Q2h, Q2l,
                                      r[0], r[1], r[2], r[6], r[7], r[8]);
    // d5: B = Q2·U + r12·Q2^2 + V
    bfin32<<<256, 512, 0, stream>>>(Q2h, Q2l, Uh, Ul, Vh, Vl, Bh, Bl, r[12]);
    // d6: out = X·B
    final32<<<1024, 256, 0, stream>>>(Xhi, Xlo, Bh, Bl, out);
}